// Round 12
// baseline (41.854 us; speedup 1.0000x reference)
//
#include <hip/hip_runtime.h>
#include <math.h>

#define BB 2048
#define DD 512
#define NS 7
#define KK 1024   // GEMM K (elements == bytes in fp8)
#define BM 128
#define BN 64
#define BK 64
#define NT (KK / BK)  // 16 K-steps

typedef __attribute__((ext_vector_type(8))) short short8;
typedef __attribute__((ext_vector_type(4))) float floatx4;
typedef long long i64;

typedef const __attribute__((address_space(1))) void gv_t;
typedef __attribute__((address_space(3))) void lv_t;
__device__ __forceinline__ void gl2lds16(const void* g, void* l) {
  __builtin_amdgcn_global_load_lds((gv_t*)g, (lv_t*)l, 16, 0, 0);
}

__device__ __forceinline__ unsigned short f2bf(float f) {
  unsigned int u = __float_as_uint(f);
  u += 0x7FFFu + ((u >> 16) & 1u);  // RNE
  return (unsigned short)(u >> 16);
}
__device__ __forceinline__ float bf2f(unsigned short u) {
  return __uint_as_float(((unsigned)u) << 16);
}

// monotone float<->uint key for atomicMax over signed floats
__device__ __forceinline__ unsigned fkey(float f) {
  unsigned u = __float_as_uint(f);
  return (u & 0x80000000u) ? ~u : (u | 0x80000000u);
}
__device__ __forceinline__ float funkey(unsigned k) {
  unsigned u = (k & 0x80000000u) ? (k ^ 0x80000000u) : ~k;
  return __uint_as_float(u);
}

// 8 floats -> 8 fp8 e4m3 (OCP, RNE)
__device__ __forceinline__ uint2 pack8_fp8(const float* v) {
  int lo = 0, hi = 0;
  lo = __builtin_amdgcn_cvt_pk_fp8_f32(v[0], v[1], lo, false);
  lo = __builtin_amdgcn_cvt_pk_fp8_f32(v[2], v[3], lo, true);
  hi = __builtin_amdgcn_cvt_pk_fp8_f32(v[4], v[5], hi, false);
  hi = __builtin_amdgcn_cvt_pk_fp8_f32(v[6], v[7], hi, true);
  uint2 r; r.x = (unsigned)lo; r.y = (unsigned)hi; return r;
}

// Round-9 swizzle (verbatim): within each 64B K-group of a row, XOR the
// 16B-chunk index (2b) with row&3 and the 8B-half bit with (row>>2)&1.
// Bank-pair analysis: claims are exactly 4 per pair = the b64 floor.

__device__ __forceinline__ float wsum(float v) {
#pragma unroll
  for (int off = 32; off > 0; off >>= 1) v += __shfl_xor(v, off, 64);
  return v;
}
__device__ __forceinline__ float wmax(float v) {
#pragma unroll
  for (int off = 32; off > 0; off >>= 1) v = fmaxf(v, __shfl_xor(v, off, 64));
  return v;
}

// ---------------------------------------------------------------------------
// Kernel 1: wave-per-row prep (round-9 verbatim + cnt zeroing).
__global__ __launch_bounds__(256) void prep(
    const float* __restrict__ qmean, const float* __restrict__ qls,
    const float* __restrict__ tmean, const float* __restrict__ tls,
    const float* __restrict__ eps,
    unsigned char* __restrict__ Acat, unsigned char* __restrict__ Bcat,
    float* __restrict__ qterm, unsigned* __restrict__ Mkey,
    unsigned* __restrict__ cnt) {
  const int w = threadIdx.x >> 6, lane = threadIdx.x & 63;
  const int r = blockIdx.x * 4 + w;  // 0..4095
  const int grp = (lane >> 3) * 64;
  const int physoff = (((((lane & 7) >> 1) ^ r) & 3) << 4) |
                      ((((lane & 7) ^ (r >> 2)) & 1) << 3);
  if (r < BB) {
    const int q = r;
    if (q == 0) cnt[lane] = 0u;  // zero arrive counters [0..32] for this replay
    const float4* xm = (const float4*)(qmean + (size_t)q * DD);
    const float4* xl = (const float4*)(qls + (size_t)q * DD);
    float4 a0 = xm[2 * lane], a1 = xm[2 * lane + 1];
    float4 l0 = xl[2 * lane], l1 = xl[2 * lane + 1];
    float x[8] = {a0.x, a0.y, a0.z, a0.w, a1.x, a1.y, a1.z, a1.w};
    float l[8] = {l0.x, l0.y, l0.z, l0.w, l1.x, l1.y, l1.z, l1.w};
    float ss = 0.f;
#pragma unroll
    for (int e = 0; e < 8; ++e) ss += x[e] * x[e];
    ss = wsum(ss);
    float inv = 1.0f / fmaxf(sqrtf(ss), 1e-12f);
    float W[8], M2[8], qt = 0.f;
#pragma unroll
    for (int e = 0; e < 8; ++e) {
      W[e] = expf(-l[e]);
      float n = x[e] * inv;
      M2[e] = -2.0f * n * W[e];
      qt += n * n * W[e];
    }
    qt = wsum(qt);
    if (lane == 0) qterm[q] = qt;
    unsigned char* arow = Acat + (size_t)q * KK;
    *(uint2*)(arow + grp + physoff)       = pack8_fp8(W);
    *(uint2*)(arow + 512 + grp + physoff) = pack8_fp8(M2);
  } else {
    const int t = r - BB;
    if (lane == 0) Mkey[t] = 0u;  // below fkey of any finite float
    const float4* xm = (const float4*)(tmean + (size_t)t * DD);
    const float4* xl = (const float4*)(tls + (size_t)t * DD);
    float4 a0 = xm[2 * lane], a1 = xm[2 * lane + 1];
    float4 l0 = xl[2 * lane], l1 = xl[2 * lane + 1];
    float x[8] = {a0.x, a0.y, a0.z, a0.w, a1.x, a1.y, a1.z, a1.w};
    float l[8] = {l0.x, l0.y, l0.z, l0.w, l1.x, l1.y, l1.z, l1.w};
    float ss = 0.f;
#pragma unroll
    for (int e = 0; e < 8; ++e) ss += x[e] * x[e];
    ss = wsum(ss);
    float inv = 1.0f / fmaxf(sqrtf(ss), 1e-12f);
    float se[8], sq[8];
#pragma unroll
    for (int e = 0; e < 8; ++e) { se[e] = 0.f; sq[e] = 0.f; }
    const float4* ep = (const float4*)(eps + (size_t)t * NS * DD);
#pragma unroll
    for (int s = 0; s < NS; ++s) {
      float4 e0 = ep[s * (DD / 4) + 2 * lane];
      float4 e1 = ep[s * (DD / 4) + 2 * lane + 1];
      float ev[8] = {e0.x, e0.y, e0.z, e0.w, e1.x, e1.y, e1.z, e1.w};
#pragma unroll
      for (int e = 0; e < 8; ++e) { se[e] += ev[e]; sq[e] += ev[e] * ev[e]; }
    }
    const float i7 = 1.0f / 7.0f;
    float S2[8], S1[8];
#pragma unroll
    for (int e = 0; e < 8; ++e) {
      float tm = x[e] * inv;
      float sg = expf(l[e]);
      float m1 = sg * se[e] * i7;
      S1[e] = tm + m1;
      S2[e] = (tm * tm + 2.0f * tm * m1 + sg * sg * sq[e] * i7) * 0.00390625f;
    }
    unsigned char* brow = Bcat + (size_t)t * KK;
    *(uint2*)(brow + grp + physoff)       = pack8_fp8(S2);
    *(uint2*)(brow + 512 + grp + physoff) = pack8_fp8(S1);
  }
}

// ---------------------------------------------------------------------------
// Kernel 2: fp8 GEMM (round-9 verbatim: the 34.9us configuration).
// 128x64 tile, 4 waves, grid 512 (2/CU), BK=64, triple-buffered LDS (36 KB),
// counted vmcnt(3), setprio, XCD 8x8 rectangles, split accumulators.
__global__ __launch_bounds__(256) void gemm_loc(
    const unsigned char* __restrict__ Acat,
    const unsigned char* __restrict__ Bcat,
    const float* __restrict__ qterm,
    unsigned short* __restrict__ loc, unsigned* __restrict__ Mkey) {
  __shared__ __align__(16) char As[3][BM * BK];  // 3 x 8 KB
  __shared__ __align__(16) char Bs[3][BN * BK];  // 3 x 4 KB
  const int tid = threadIdx.x, lane = tid & 63, wid = tid >> 6;
  const int lin = blockIdx.y * (BB / BN) + blockIdx.x;  // 0..511
  const int xcd = lin & 7, j = lin >> 3;
  const int tr = ((xcd >> 2) << 3) + (j >> 3);          // tile row 0..15
  const int tc = ((xcd & 3) << 3) + (j & 7);            // tile col 0..31
  const int brow = tr * BM, bcol = tc * BN;
  const int wr = wid >> 1, wc = wid & 1;                // wave 64x32 sub-tile
  const int fr = lane & 15, kg = lane >> 4;

  floatx4 acc[2][4][2];
#pragma unroll
  for (int h = 0; h < 2; ++h)
#pragma unroll
    for (int m = 0; m < 4; ++m)
#pragma unroll
      for (int n = 0; n < 2; ++n) acc[h][m][n] = (floatx4){0.f, 0.f, 0.f, 0.f};

  const unsigned char* gA0 = Acat + (size_t)(brow + (tid >> 2)) * KK + (tid & 3) * 16;
  const unsigned char* gA1 = gA0 + (size_t)64 * KK;
  const unsigned char* gB0 = Bcat + (size_t)(bcol + (tid >> 2)) * KK + (tid & 3) * 16;

#define STAGE(buf, kc)                                      \
  {                                                         \
    gl2lds16(gA0 + (kc), &As[buf][tid * 16]);               \
    gl2lds16(gA1 + (kc), &As[buf][4096 + tid * 16]);        \
    gl2lds16(gB0 + (kc), &Bs[buf][tid * 16]);               \
  }

  STAGE(0, 0)
  STAGE(1, BK)

#pragma unroll
  for (int kt = 0; kt < NT; ++kt) {
    if (kt < NT - 1) asm volatile("s_waitcnt vmcnt(3)" ::: "memory");
    else             asm volatile("s_waitcnt vmcnt(0)" ::: "memory");
    __builtin_amdgcn_s_barrier();
    if (kt + 2 < NT) { STAGE((kt + 2) % 3, (kt + 2) * BK) }
    const char* a  = As[kt % 3];
    const char* bp = Bs[kt % 3];
#pragma unroll
    for (int kh = 0; kh < 2; ++kh) {
      const int co = ((((kh * 2 + (kg >> 1)) ^ fr) & 3) << 4) |
                     (((kg ^ (fr >> 2)) & 1) << 3);
      i64 af[4], bf[2];
#pragma unroll
      for (int m = 0; m < 4; ++m)
        af[m] = *(const i64*)(a + (wr * 64 + m * 16 + fr) * BK + co);
#pragma unroll
      for (int n = 0; n < 2; ++n)
        bf[n] = *(const i64*)(bp + (wc * 32 + n * 16 + fr) * BK + co);
      __builtin_amdgcn_s_setprio(1);
#pragma unroll
      for (int m = 0; m < 4; ++m)
#pragma unroll
        for (int n = 0; n < 2; ++n)
          acc[kt >> 3][m][n] = __builtin_amdgcn_mfma_f32_16x16x32_fp8_fp8(
              af[m], bf[n], acc[kt >> 3][m][n], 0, 0, 0);
      __builtin_amdgcn_s_setprio(0);
    }
  }
#undef STAGE

  // epilogue: recombine halves (S2 stored /256), write bf16 loc, fuse col max
#pragma unroll
  for (int n = 0; n < 2; ++n) {
    const int col = bcol + wc * 32 + n * 16 + fr;
    float cm = -3.402823466e38f;
#pragma unroll
    for (int m = 0; m < 4; ++m) {
      const int row = brow + wr * 64 + m * 16 + kg * 4;
#pragma unroll
      for (int r4 = 0; r4 < 4; ++r4) {
        float v = -0.5f * (256.0f * acc[0][m][n][r4] + acc[1][m][n][r4] +
                           qterm[row + r4]);
        loc[(size_t)(row + r4) * BB + col] = f2bf(v);
        cm = fmaxf(cm, v);
      }
    }
    cm = fmaxf(cm, __shfl_xor(cm, 16, 64));
    cm = fmaxf(cm, __shfl_xor(cm, 32, 64));
    if (kg == 0) atomicMax(&Mkey[col], fkey(cm));  // order-invariant
  }
}

// ---------------------------------------------------------------------------
// Kernel 3: wave-per-row LSE + diag + fused final mean (round-11 component).
// rowval via distinct-address atomicExch (pipelined, MALL-coherent);
// hierarchical 32+1 arrive ticket (no spinning); uniquely-last block reduces.
__global__ __launch_bounds__(256) void row_lse(
    const unsigned short* __restrict__ loc, const unsigned* __restrict__ Mkey,
    unsigned* __restrict__ rowval, unsigned* __restrict__ cnt,
    float* __restrict__ out) {
  __shared__ int lastflag;
  __shared__ float sb[4];
  const int w = threadIdx.x >> 6, lane = threadIdx.x & 63, tid = threadIdx.x;
  const int q = blockIdx.x * 4 + w;
  const short8* lp = (const short8*)(loc + (size_t)q * BB);
  const uint4* kp = (const uint4*)Mkey;
  float xs[4][8];
  float m = -3.402823466e38f, dv = 0.f;
#pragma unroll
  for (int c = 0; c < 4; ++c) {
    short8 v = lp[c * 64 + lane];
    uint4 k0 = kp[(c * 64 + lane) * 2];
    uint4 k1 = kp[(c * 64 + lane) * 2 + 1];
    unsigned ks[8] = {k0.x, k0.y, k0.z, k0.w, k1.x, k1.y, k1.z, k1.w};
#pragma unroll
    for (int e = 0; e < 8; ++e) {
      float x = bf2f((unsigned short)v[e]) - funkey(ks[e]);
      xs[c][e] = x;
      m = fmaxf(m, x);
      if (c * 512 + lane * 8 + e == q) dv = x;  // diag (static idx)
    }
  }
  m = wmax(m);
  float s = 0.f;
#pragma unroll
  for (int c = 0; c < 4; ++c)
#pragma unroll
    for (int e = 0; e < 8; ++e) s += expf(xs[c][e] - m);
  s = wsum(s);
  float d = __shfl(dv, (q >> 3) & 63, 64);
  if (lane == 0)
    atomicExch(&rowval[q], __float_as_uint(d - (m + logf(s))));

  // arrive; only the uniquely-last block continues to the final reduce
  __syncthreads();
  if (tid == 0) {
    __threadfence();
    int last = 0;
    unsigned t1 = atomicAdd(&cnt[blockIdx.x & 31], 1u);
    if (t1 == 15u) {
      unsigned t2 = atomicAdd(&cnt[32], 1u);
      last = (t2 == 31u);
    }
    lastflag = last;
  }
  __syncthreads();
  if (!lastflag) return;
  __threadfence();

  float fs = 0.f;
#pragma unroll
  for (int i = 0; i < 8; ++i) {
    unsigned u = __hip_atomic_load(&rowval[tid + i * 256], __ATOMIC_RELAXED,
                                   __HIP_MEMORY_SCOPE_AGENT);
    fs += __uint_as_float(u);
  }
  fs = wsum(fs);
  if (lane == 0) sb[w] = fs;
  __syncthreads();
  if (tid == 0) out[0] = -(sb[0] + sb[1] + sb[2] + sb[3]) * (1.0f / (float)BB);
}

// ---------------------------------------------------------------------------
extern "C" void kernel_launch(void* const* d_in, const int* in_sizes, int n_in,
                              void* d_out, int out_size, void* d_ws, size_t ws_size,
                              hipStream_t stream) {
  const float* qmean = (const float*)d_in[0];
  const float* qls   = (const float*)d_in[1];
  // d_in[2] query_z: cancels (broadcasts on target axis -> drops in colmax+softmax)
  const float* tmean = (const float*)d_in[3];
  const float* tls   = (const float*)d_in[4];
  // d_in[5] target_z: unused by reference
  const float* eps   = (const float*)d_in[6];

  char* ws = (char*)d_ws;
  unsigned char* Acat = (unsigned char*)(ws);                        // 2 MB
  unsigned char* Bcat = (unsigned char*)(ws + (2u << 20));           // 2 MB
  float* qterm   = (float*)(ws + (4u << 20));                        // 8 KB
  unsigned* Mkey = (unsigned*)(ws + (4u << 20) + 8192);              // 8 KB
  unsigned* rowval = (unsigned*)(ws + (4u << 20) + 16384);           // 8 KB
  unsigned* cnt  = (unsigned*)(ws + (4u << 20) + 24576);             // 256 B
  unsigned short* loc = (unsigned short*)(ws + (4u << 20) + 65536);  // 8 MB

  prep<<<1024, 256, 0, stream>>>(qmean, qls, tmean, tls, eps,
                                 Acat, Bcat, qterm, Mkey, cnt);
  gemm_loc<<<dim3(BB / BN, BB / BM), 256, 0, stream>>>(Acat, Bcat, qterm, loc, Mkey);
  row_lse<<<512, 256, 0, stream>>>(loc, Mkey, rowval, cnt, (float*)d_out);
}

// Round 15
// 33.723 us; speedup vs baseline: 1.2411x; 1.2411x over previous
//
#include <hip/hip_runtime.h>
#include <math.h>

#define BB 2048
#define DD 512
#define NS 7
#define KK 1024   // GEMM K (elements == bytes in fp8)
#define BM 128
#define BN 64
#define BK 64
#define NT (KK / BK)  // 16 K-steps

typedef __attribute__((ext_vector_type(8))) short short8;
typedef __attribute__((ext_vector_type(4))) float floatx4;
typedef long long i64;

typedef const __attribute__((address_space(1))) void gv_t;
typedef __attribute__((address_space(3))) void lv_t;
__device__ __forceinline__ void gl2lds16(const void* g, void* l) {
  __builtin_amdgcn_global_load_lds((gv_t*)g, (lv_t*)l, 16, 0, 0);
}

__device__ __forceinline__ unsigned short f2bf(float f) {
  unsigned int u = __float_as_uint(f);
  u += 0x7FFFu + ((u >> 16) & 1u);  // RNE
  return (unsigned short)(u >> 16);
}
__device__ __forceinline__ float bf2f(unsigned short u) {
  return __uint_as_float(((unsigned)u) << 16);
}

// fast transcendentals via HW v_exp_f32 / v_log_f32 (both base-2 on gfx950:
// __builtin_amdgcn_exp2f(x)=2^x, __builtin_amdgcn_logf(x)=log2(x) per
// __clang_hip_math.h). ~2 ulp; negligible vs the 26.88 absolute threshold.
__device__ __forceinline__ float fexp(float x) {
  return __builtin_amdgcn_exp2f(x * 1.44269504088896341f);   // e^x = 2^(x*log2e)
}
__device__ __forceinline__ float flog(float x) {
  return __builtin_amdgcn_logf(x) * 0.69314718055994531f;    // ln x = ln2*log2 x
}

// monotone float<->uint key for atomicMax over signed floats
__device__ __forceinline__ unsigned fkey(float f) {
  unsigned u = __float_as_uint(f);
  return (u & 0x80000000u) ? ~u : (u | 0x80000000u);
}
__device__ __forceinline__ float funkey(unsigned k) {
  unsigned u = (k & 0x80000000u) ? (k ^ 0x80000000u) : ~k;
  return __uint_as_float(u);
}

// 8 floats -> 8 fp8 e4m3 (OCP, RNE)
__device__ __forceinline__ uint2 pack8_fp8(const float* v) {
  int lo = 0, hi = 0;
  lo = __builtin_amdgcn_cvt_pk_fp8_f32(v[0], v[1], lo, false);
  lo = __builtin_amdgcn_cvt_pk_fp8_f32(v[2], v[3], lo, true);
  hi = __builtin_amdgcn_cvt_pk_fp8_f32(v[4], v[5], hi, false);
  hi = __builtin_amdgcn_cvt_pk_fp8_f32(v[6], v[7], hi, true);
  uint2 r; r.x = (unsigned)lo; r.y = (unsigned)hi; return r;
}

// Round-9 swizzle: within each 64B K-group of a row, XOR the 16B-chunk index
// (2b) with row&3 and the 8B-half bit with (row>>2)&1. Bank-pair claims are
// exactly 4 per pair = the ds_read_b64 floor.

__device__ __forceinline__ float wsum(float v) {
#pragma unroll
  for (int off = 32; off > 0; off >>= 1) v += __shfl_xor(v, off, 64);
  return v;
}
__device__ __forceinline__ float wmax(float v) {
#pragma unroll
  for (int off = 32; off > 0; off >>= 1) v = fmaxf(v, __shfl_xor(v, off, 64));
  return v;
}
__device__ __forceinline__ float block_reduce_sum256(float v, float* sbuf) {
  v = wsum(v);
  if ((threadIdx.x & 63) == 0) sbuf[threadIdx.x >> 6] = v;
  __syncthreads();
  float r = sbuf[0] + sbuf[1] + sbuf[2] + sbuf[3];
  __syncthreads();
  return r;
}

// ---------------------------------------------------------------------------
// Kernel 1: wave-per-row prep (round-9 verbatim, fast-exp). 1024 blocks.
__global__ __launch_bounds__(256) void prep(
    const float* __restrict__ qmean, const float* __restrict__ qls,
    const float* __restrict__ tmean, const float* __restrict__ tls,
    const float* __restrict__ eps,
    unsigned char* __restrict__ Acat, unsigned char* __restrict__ Bcat,
    float* __restrict__ qterm, unsigned* __restrict__ Mkey) {
  const int w = threadIdx.x >> 6, lane = threadIdx.x & 63;
  const int r = blockIdx.x * 4 + w;  // 0..4095
  const int grp = (lane >> 3) * 64;
  const int physoff = (((((lane & 7) >> 1) ^ r) & 3) << 4) |
                      ((((lane & 7) ^ (r >> 2)) & 1) << 3);
  if (r < BB) {
    const int q = r;
    const float4* xm = (const float4*)(qmean + (size_t)q * DD);
    const float4* xl = (const float4*)(qls + (size_t)q * DD);
    float4 a0 = xm[2 * lane], a1 = xm[2 * lane + 1];
    float4 l0 = xl[2 * lane], l1 = xl[2 * lane + 1];
    float x[8] = {a0.x, a0.y, a0.z, a0.w, a1.x, a1.y, a1.z, a1.w};
    float l[8] = {l0.x, l0.y, l0.z, l0.w, l1.x, l1.y, l1.z, l1.w};
    float ss = 0.f;
#pragma unroll
    for (int e = 0; e < 8; ++e) ss += x[e] * x[e];
    ss = wsum(ss);
    float inv = 1.0f / fmaxf(sqrtf(ss), 1e-12f);
    float W[8], M2[8], qt = 0.f;
#pragma unroll
    for (int e = 0; e < 8; ++e) {
      W[e] = fexp(-l[e]);
      float n = x[e] * inv;
      M2[e] = -2.0f * n * W[e];
      qt += n * n * W[e];
    }
    qt = wsum(qt);
    if (lane == 0) qterm[q] = qt;
    unsigned char* arow = Acat + (size_t)q * KK;
    *(uint2*)(arow + grp + physoff)       = pack8_fp8(W);
    *(uint2*)(arow + 512 + grp + physoff) = pack8_fp8(M2);
  } else {
    const int t = r - BB;
    if (lane == 0) Mkey[t] = 0u;  // below fkey of any finite float
    const float4* xm = (const float4*)(tmean + (size_t)t * DD);
    const float4* xl = (const float4*)(tls + (size_t)t * DD);
    float4 a0 = xm[2 * lane], a1 = xm[2 * lane + 1];
    float4 l0 = xl[2 * lane], l1 = xl[2 * lane + 1];
    float x[8] = {a0.x, a0.y, a0.z, a0.w, a1.x, a1.y, a1.z, a1.w};
    float l[8] = {l0.x, l0.y, l0.z, l0.w, l1.x, l1.y, l1.z, l1.w};
    float ss = 0.f;
#pragma unroll
    for (int e = 0; e < 8; ++e) ss += x[e] * x[e];
    ss = wsum(ss);
    float inv = 1.0f / fmaxf(sqrtf(ss), 1e-12f);
    float se[8], sq[8];
#pragma unroll
    for (int e = 0; e < 8; ++e) { se[e] = 0.f; sq[e] = 0.f; }
    const float4* ep = (const float4*)(eps + (size_t)t * NS * DD);
#pragma unroll
    for (int s = 0; s < NS; ++s) {
      float4 e0 = ep[s * (DD / 4) + 2 * lane];
      float4 e1 = ep[s * (DD / 4) + 2 * lane + 1];
      float ev[8] = {e0.x, e0.y, e0.z, e0.w, e1.x, e1.y, e1.z, e1.w};
#pragma unroll
      for (int e = 0; e < 8; ++e) { se[e] += ev[e]; sq[e] += ev[e] * ev[e]; }
    }
    const float i7 = 1.0f / 7.0f;
    float S2[8], S1[8];
#pragma unroll
    for (int e = 0; e < 8; ++e) {
      float tm = x[e] * inv;
      float sg = fexp(l[e]);
      float m1 = sg * se[e] * i7;
      S1[e] = tm + m1;
      S2[e] = (tm * tm + 2.0f * tm * m1 + sg * sg * sq[e] * i7) * 0.00390625f;
    }
    unsigned char* brow = Bcat + (size_t)t * KK;
    *(uint2*)(brow + grp + physoff)       = pack8_fp8(S2);
    *(uint2*)(brow + 512 + grp + physoff) = pack8_fp8(S1);
  }
}

// ---------------------------------------------------------------------------
// Kernel 2: fp8 GEMM (round-9 verbatim: the 34.9us configuration).
__global__ __launch_bounds__(256) void gemm_loc(
    const unsigned char* __restrict__ Acat,
    const unsigned char* __restrict__ Bcat,
    const float* __restrict__ qterm,
    unsigned short* __restrict__ loc, unsigned* __restrict__ Mkey) {
  __shared__ __align__(16) char As[3][BM * BK];  // 3 x 8 KB
  __shared__ __align__(16) char Bs[3][BN * BK];  // 3 x 4 KB
  const int tid = threadIdx.x, lane = tid & 63, wid = tid >> 6;
  const int lin = blockIdx.y * (BB / BN) + blockIdx.x;  // 0..511
  const int xcd = lin & 7, j = lin >> 3;
  const int tr = ((xcd >> 2) << 3) + (j >> 3);          // tile row 0..15
  const int tc = ((xcd & 3) << 3) + (j & 7);            // tile col 0..31
  const int brow = tr * BM, bcol = tc * BN;
  const int wr = wid >> 1, wc = wid & 1;                // wave 64x32 sub-tile
  const int fr = lane & 15, kg = lane >> 4;

  floatx4 acc[2][4][2];
#pragma unroll
  for (int h = 0; h < 2; ++h)
#pragma unroll
    for (int m = 0; m < 4; ++m)
#pragma unroll
      for (int n = 0; n < 2; ++n) acc[h][m][n] = (floatx4){0.f, 0.f, 0.f, 0.f};

  const unsigned char* gA0 = Acat + (size_t)(brow + (tid >> 2)) * KK + (tid & 3) * 16;
  const unsigned char* gA1 = gA0 + (size_t)64 * KK;
  const unsigned char* gB0 = Bcat + (size_t)(bcol + (tid >> 2)) * KK + (tid & 3) * 16;

#define STAGE(buf, kc)                                      \
  {                                                         \
    gl2lds16(gA0 + (kc), &As[buf][tid * 16]);               \
    gl2lds16(gA1 + (kc), &As[buf][4096 + tid * 16]);        \
    gl2lds16(gB0 + (kc), &Bs[buf][tid * 16]);               \
  }

  STAGE(0, 0)
  STAGE(1, BK)

#pragma unroll
  for (int kt = 0; kt < NT; ++kt) {
    if (kt < NT - 1) asm volatile("s_waitcnt vmcnt(3)" ::: "memory");
    else             asm volatile("s_waitcnt vmcnt(0)" ::: "memory");
    __builtin_amdgcn_s_barrier();
    if (kt + 2 < NT) { STAGE((kt + 2) % 3, (kt + 2) * BK) }
    const char* a  = As[kt % 3];
    const char* bp = Bs[kt % 3];
#pragma unroll
    for (int kh = 0; kh < 2; ++kh) {
      const int co = ((((kh * 2 + (kg >> 1)) ^ fr) & 3) << 4) |
                     (((kg ^ (fr >> 2)) & 1) << 3);
      i64 af[4], bf[2];
#pragma unroll
      for (int m = 0; m < 4; ++m)
        af[m] = *(const i64*)(a + (wr * 64 + m * 16 + fr) * BK + co);
#pragma unroll
      for (int n = 0; n < 2; ++n)
        bf[n] = *(const i64*)(bp + (wc * 32 + n * 16 + fr) * BK + co);
      __builtin_amdgcn_s_setprio(1);
#pragma unroll
      for (int m = 0; m < 4; ++m)
#pragma unroll
        for (int n = 0; n < 2; ++n)
          acc[kt >> 3][m][n] = __builtin_amdgcn_mfma_f32_16x16x32_fp8_fp8(
              af[m], bf[n], acc[kt >> 3][m][n], 0, 0, 0);
      __builtin_amdgcn_s_setprio(0);
    }
  }
#undef STAGE

  // epilogue: recombine halves (S2 stored /256), write bf16 loc, fuse col max
#pragma unroll
  for (int n = 0; n < 2; ++n) {
    const int col = bcol + wc * 32 + n * 16 + fr;
    float cm = -3.402823466e38f;
#pragma unroll
    for (int m = 0; m < 4; ++m) {
      const int row = brow + wr * 64 + m * 16 + kg * 4;
#pragma unroll
      for (int r4 = 0; r4 < 4; ++r4) {
        float v = -0.5f * (256.0f * acc[0][m][n][r4] + acc[1][m][n][r4] +
                           qterm[row + r4]);
        loc[(size_t)(row + r4) * BB + col] = f2bf(v);
        cm = fmaxf(cm, v);
      }
    }
    cm = fmaxf(cm, __shfl_xor(cm, 16, 64));
    cm = fmaxf(cm, __shfl_xor(cm, 32, 64));
    if (kg == 0) atomicMax(&Mkey[col], fkey(cm));  // order-invariant
  }
}

// ---------------------------------------------------------------------------
// Kernel 3: wave-per-row LSE + diag (round-9 verbatim, fast-exp/log).
__global__ __launch_bounds__(256) void row_lse(
    const unsigned short* __restrict__ loc, const unsigned* __restrict__ Mkey,
    float* __restrict__ rowval) {
  const int w = threadIdx.x >> 6, lane = threadIdx.x & 63;
  const int q = blockIdx.x * 4 + w;
  const short8* lp = (const short8*)(loc + (size_t)q * BB);
  const uint4* kp = (const uint4*)Mkey;
  float xs[4][8];
  float m = -3.402823466e38f, dv = 0.f;
#pragma unroll
  for (int c = 0; c < 4; ++c) {
    short8 v = lp[c * 64 + lane];
    uint4 k0 = kp[(c * 64 + lane) * 2];
    uint4 k1 = kp[(c * 64 + lane) * 2 + 1];
    unsigned ks[8] = {k0.x, k0.y, k0.z, k0.w, k1.x, k1.y, k1.z, k1.w};
#pragma unroll
    for (int e = 0; e < 8; ++e) {
      float x = bf2f((unsigned short)v[e]) - funkey(ks[e]);
      xs[c][e] = x;
      m = fmaxf(m, x);
      if (c * 512 + lane * 8 + e == q) dv = x;  // diag (static idx)
    }
  }
  m = wmax(m);
  float s = 0.f;
#pragma unroll
  for (int c = 0; c < 4; ++c)
#pragma unroll
    for (int e = 0; e < 8; ++e) s += fexp(xs[c][e] - m);
  s = wsum(s);
  float d = __shfl(dv, (q >> 3) & 63, 64);
  if (lane == 0) rowval[q] = d - (m + flog(s));
}

// ---------------------------------------------------------------------------
// Kernel 4: loss = -mean_q rowval[q]  (single block)
__global__ __launch_bounds__(256) void final_loss(
    const float* __restrict__ rowval, float* __restrict__ out) {
  __shared__ float sbuf[4];
  const int tid = threadIdx.x;
  float s = 0.f;
#pragma unroll
  for (int i = 0; i < 8; ++i) s += rowval[tid + i * 256];
  s = block_reduce_sum256(s, sbuf);
  if (tid == 0) out[0] = -s * (1.0f / (float)BB);
}

// ---------------------------------------------------------------------------
extern "C" void kernel_launch(void* const* d_in, const int* in_sizes, int n_in,
                              void* d_out, int out_size, void* d_ws, size_t ws_size,
                              hipStream_t stream) {
  const float* qmean = (const float*)d_in[0];
  const float* qls   = (const float*)d_in[1];
  // d_in[2] query_z: cancels (broadcasts on target axis -> drops in colmax+softmax)
  const float* tmean = (const float*)d_in[3];
  const float* tls   = (const float*)d_in[4];
  // d_in[5] target_z: unused by reference
  const float* eps   = (const float*)d_in[6];

  char* ws = (char*)d_ws;
  unsigned char* Acat  = (unsigned char*)(ws + 0);                   // 2 MB
  unsigned char* Bcat  = (unsigned char*)(ws + (2u << 20));          // 2 MB
  float* qterm         = (float*)(ws + (4u << 20));                  // 8 KB
  unsigned* Mkey       = (unsigned*)(ws + (4u << 20) + 8192);        // 8 KB
  float* rowval        = (float*)(ws + (4u << 20) + 16384);          // 8 KB
  unsigned short* loc  = (unsigned short*)(ws + (4u << 20) + 65536); // 8 MB

  prep<<<1024, 256, 0, stream>>>(qmean, qls, tmean, tls, eps,
                                 Acat, Bcat, qterm, Mkey);
  gemm_loc<<<dim3(BB / BN, BB / BM), 256, 0, stream>>>(Acat, Bcat, qterm, loc, Mkey);
  row_lse<<<512, 256, 0, stream>>>(loc, Mkey, rowval);
  final_loss<<<1, 256, 0, stream>>>(rowval, (float*)d_out);
}

// Round 17
// 33.320 us; speedup vs baseline: 1.2561x; 1.0121x over previous
//
#include <hip/hip_runtime.h>
#include <math.h>

#define BB 2048
#define DD 512
#define NS 7
#define KK 1024   // GEMM K (elements == bytes in fp8)
#define BM 64
#define BN 64
#define BK 64
#define NT (KK / BK)  // 16 K-steps

typedef __attribute__((ext_vector_type(8))) short short8;
typedef __attribute__((ext_vector_type(4))) float floatx4;
typedef long long i64;

typedef const __attribute__((address_space(1))) void gv_t;
typedef __attribute__((address_space(3))) void lv_t;
__device__ __forceinline__ void gl2lds16(const void* g, void* l) {
  __builtin_amdgcn_global_load_lds((gv_t*)g, (lv_t*)l, 16, 0, 0);
}

__device__ __forceinline__ unsigned short f2bf(float f) {
  unsigned int u = __float_as_uint(f);
  u += 0x7FFFu + ((u >> 16) & 1u);  // RNE
  return (unsigned short)(u >> 16);
}
__device__ __forceinline__ float bf2f(unsigned short u) {
  return __uint_as_float(((unsigned)u) << 16);
}

// fast transcendentals via HW v_exp_f32 / v_log_f32 (base-2 on gfx950)
__device__ __forceinline__ float fexp(float x) {
  return __builtin_amdgcn_exp2f(x * 1.44269504088896341f);   // e^x = 2^(x*log2e)
}
__device__ __forceinline__ float flog(float x) {
  return __builtin_amdgcn_logf(x) * 0.69314718055994531f;    // ln x = ln2*log2 x
}

// monotone float<->uint key for atomicMax over signed floats
__device__ __forceinline__ unsigned fkey(float f) {
  unsigned u = __float_as_uint(f);
  return (u & 0x80000000u) ? ~u : (u | 0x80000000u);
}
__device__ __forceinline__ float funkey(unsigned k) {
  unsigned u = (k & 0x80000000u) ? (k ^ 0x80000000u) : ~k;
  return __uint_as_float(u);
}

// 8 floats -> 8 fp8 e4m3 (OCP, RNE)
__device__ __forceinline__ uint2 pack8_fp8(const float* v) {
  int lo = 0, hi = 0;
  lo = __builtin_amdgcn_cvt_pk_fp8_f32(v[0], v[1], lo, false);
  lo = __builtin_amdgcn_cvt_pk_fp8_f32(v[2], v[3], lo, true);
  hi = __builtin_amdgcn_cvt_pk_fp8_f32(v[4], v[5], hi, false);
  hi = __builtin_amdgcn_cvt_pk_fp8_f32(v[6], v[7], hi, true);
  uint2 r; r.x = (unsigned)lo; r.y = (unsigned)hi; return r;
}

// Round-9 swizzle: within each 64B K-group of a row, XOR the 16B-chunk index
// (2b) with row&3 and the 8B-half bit with (row>>2)&1. All fragment-row tile
// offsets are multiples of 16, so row&7 == fr&7 in the un-swizzle.

__device__ __forceinline__ float wsum(float v) {
#pragma unroll
  for (int off = 32; off > 0; off >>= 1) v += __shfl_xor(v, off, 64);
  return v;
}
__device__ __forceinline__ float wmax(float v) {
#pragma unroll
  for (int off = 32; off > 0; off >>= 1) v = fmaxf(v, __shfl_xor(v, off, 64));
  return v;
}
__device__ __forceinline__ float block_reduce_sum256(float v, float* sbuf) {
  v = wsum(v);
  if ((threadIdx.x & 63) == 0) sbuf[threadIdx.x >> 6] = v;
  __syncthreads();
  float r = sbuf[0] + sbuf[1] + sbuf[2] + sbuf[3];
  __syncthreads();
  return r;
}

// ---------------------------------------------------------------------------
// Kernel 1: wave-per-row prep (round-15 verbatim). 1024 blocks.
__global__ __launch_bounds__(256) void prep(
    const float* __restrict__ qmean, const float* __restrict__ qls,
    const float* __restrict__ tmean, const float* __restrict__ tls,
    const float* __restrict__ eps,
    unsigned char* __restrict__ Acat, unsigned char* __restrict__ Bcat,
    float* __restrict__ qterm, unsigned* __restrict__ Mkey) {
  const int w = threadIdx.x >> 6, lane = threadIdx.x & 63;
  const int r = blockIdx.x * 4 + w;  // 0..4095
  const int grp = (lane >> 3) * 64;
  const int physoff = (((((lane & 7) >> 1) ^ r) & 3) << 4) |
                      ((((lane & 7) ^ (r >> 2)) & 1) << 3);
  if (r < BB) {
    const int q = r;
    const float4* xm = (const float4*)(qmean + (size_t)q * DD);
    const float4* xl = (const float4*)(qls + (size_t)q * DD);
    float4 a0 = xm[2 * lane], a1 = xm[2 * lane + 1];
    float4 l0 = xl[2 * lane], l1 = xl[2 * lane + 1];
    float x[8] = {a0.x, a0.y, a0.z, a0.w, a1.x, a1.y, a1.z, a1.w};
    float l[8] = {l0.x, l0.y, l0.z, l0.w, l1.x, l1.y, l1.z, l1.w};
    float ss = 0.f;
#pragma unroll
    for (int e = 0; e < 8; ++e) ss += x[e] * x[e];
    ss = wsum(ss);
    float inv = 1.0f / fmaxf(sqrtf(ss), 1e-12f);
    float W[8], M2[8], qt = 0.f;
#pragma unroll
    for (int e = 0; e < 8; ++e) {
      W[e] = fexp(-l[e]);
      float n = x[e] * inv;
      M2[e] = -2.0f * n * W[e];
      qt += n * n * W[e];
    }
    qt = wsum(qt);
    if (lane == 0) qterm[q] = qt;
    unsigned char* arow = Acat + (size_t)q * KK;
    *(uint2*)(arow + grp + physoff)       = pack8_fp8(W);
    *(uint2*)(arow + 512 + grp + physoff) = pack8_fp8(M2);
  } else {
    const int t = r - BB;
    if (lane == 0) Mkey[t] = 0u;  // below fkey of any finite float
    const float4* xm = (const float4*)(tmean + (size_t)t * DD);
    const float4* xl = (const float4*)(tls + (size_t)t * DD);
    float4 a0 = xm[2 * lane], a1 = xm[2 * lane + 1];
    float4 l0 = xl[2 * lane], l1 = xl[2 * lane + 1];
    float x[8] = {a0.x, a0.y, a0.z, a0.w, a1.x, a1.y, a1.z, a1.w};
    float l[8] = {l0.x, l0.y, l0.z, l0.w, l1.x, l1.y, l1.z, l1.w};
    float ss = 0.f;
#pragma unroll
    for (int e = 0; e < 8; ++e) ss += x[e] * x[e];
    ss = wsum(ss);
    float inv = 1.0f / fmaxf(sqrtf(ss), 1e-12f);
    float se[8], sq[8];
#pragma unroll
    for (int e = 0; e < 8; ++e) { se[e] = 0.f; sq[e] = 0.f; }
    const float4* ep = (const float4*)(eps + (size_t)t * NS * DD);
#pragma unroll
    for (int s = 0; s < NS; ++s) {
      float4 e0 = ep[s * (DD / 4) + 2 * lane];
      float4 e1 = ep[s * (DD / 4) + 2 * lane + 1];
      float ev[8] = {e0.x, e0.y, e0.z, e0.w, e1.x, e1.y, e1.z, e1.w};
#pragma unroll
      for (int e = 0; e < 8; ++e) { se[e] += ev[e]; sq[e] += ev[e] * ev[e]; }
    }
    const float i7 = 1.0f / 7.0f;
    float S2[8], S1[8];
#pragma unroll
    for (int e = 0; e < 8; ++e) {
      float tm = x[e] * inv;
      float sg = fexp(l[e]);
      float m1 = sg * se[e] * i7;
      S1[e] = tm + m1;
      S2[e] = (tm * tm + 2.0f * tm * m1 + sg * sg * sq[e] * i7) * 0.00390625f;
    }
    unsigned char* brow = Bcat + (size_t)t * KK;
    *(uint2*)(brow + grp + physoff)       = pack8_fp8(S2);
    *(uint2*)(brow + 512 + grp + physoff) = pack8_fp8(S1);
  }
}

// ---------------------------------------------------------------------------
// Kernel 2 (round-17): fp8 GEMM, 64x64 tile, 4 waves in a 2x2 grid — each
// wave a 32x32 QUADRANT (acc[half][2][2]; 4 x 32x32 = 64x64, geometry fixed
// from round 16). Grid 1024 = 4 blocks/CU (LDS 24KB, ~80 VGPR) -> 16
// waves/CU = 4/SIMD, double round-15's latency hiding. 0.5 ds_read/MFMA.
// Triple-buffered, counted vmcnt(2), setprio, XCD 8x16 rectangles, split
// accumulators (S2 x256 / S1).
__global__ __launch_bounds__(256) void gemm_loc(
    const unsigned char* __restrict__ Acat,
    const unsigned char* __restrict__ Bcat,
    const float* __restrict__ qterm,
    unsigned short* __restrict__ loc, unsigned* __restrict__ Mkey) {
  __shared__ __align__(16) char As[3][BM * BK];  // 3 x 4 KB
  __shared__ __align__(16) char Bs[3][BN * BK];  // 3 x 4 KB
  const int tid = threadIdx.x, lane = tid & 63, wid = tid >> 6;
  const int lin = blockIdx.x;                           // 0..1023
  const int xcd = lin & 7, j = lin >> 3;                // j 0..127
  const int tr = ((xcd >> 1) << 3) + (j >> 4);          // tile row 0..31 (8/XCD)
  const int tc = ((xcd & 1) << 4) + (j & 15);           // tile col 0..31 (16/XCD)
  const int brow = tr * BM, bcol = tc * BN;
  const int wr = wid >> 1, wc = wid & 1;                // wave 32x32 quadrant
  const int fr = lane & 15, kg = lane >> 4;

  floatx4 acc[2][2][2];
#pragma unroll
  for (int h = 0; h < 2; ++h)
#pragma unroll
    for (int m = 0; m < 2; ++m)
#pragma unroll
      for (int n = 0; n < 2; ++n) acc[h][m][n] = (floatx4){0.f, 0.f, 0.f, 0.f};

  // staging: thread covers row tid>>2 (0..63), 16B chunk (tid&3)*16
  const unsigned char* gA0 = Acat + (size_t)(brow + (tid >> 2)) * KK + (tid & 3) * 16;
  const unsigned char* gB0 = Bcat + (size_t)(bcol + (tid >> 2)) * KK + (tid & 3) * 16;

#define STAGE(buf, kc)                                      \
  {                                                         \
    gl2lds16(gA0 + (kc), &As[buf][tid * 16]);               \
    gl2lds16(gB0 + (kc), &Bs[buf][tid * 16]);               \
  }

  STAGE(0, 0)
  STAGE(1, BK)

#pragma unroll
  for (int kt = 0; kt < NT; ++kt) {
    // own tile-kt's 2 loads landed; tile kt+1's 2 may stay in flight
    if (kt < NT - 1) asm volatile("s_waitcnt vmcnt(2)" ::: "memory");
    else             asm volatile("s_waitcnt vmcnt(0)" ::: "memory");
    __builtin_amdgcn_s_barrier();
    if (kt + 2 < NT) { STAGE((kt + 2) % 3, (kt + 2) * BK) }
    const char* a  = As[kt % 3];
    const char* bp = Bs[kt % 3];
#pragma unroll
    for (int kh = 0; kh < 2; ++kh) {
      const int co = ((((kh * 2 + (kg >> 1)) ^ fr) & 3) << 4) |
                     (((kg ^ (fr >> 2)) & 1) << 3);
      i64 af[2], bf[2];
#pragma unroll
      for (int m = 0; m < 2; ++m)
        af[m] = *(const i64*)(a + (wr * 32 + m * 16 + fr) * BK + co);
#pragma unroll
      for (int n = 0; n < 2; ++n)
        bf[n] = *(const i64*)(bp + (wc * 32 + n * 16 + fr) * BK + co);
      __builtin_amdgcn_s_setprio(1);
#pragma unroll
      for (int m = 0; m < 2; ++m)
#pragma unroll
        for (int n = 0; n < 2; ++n)
          acc[kt >> 3][m][n] = __builtin_amdgcn_mfma_f32_16x16x32_fp8_fp8(
              af[m], bf[n], acc[kt >> 3][m][n], 0, 0, 0);
      __builtin_amdgcn_s_setprio(0);
    }
  }
#undef STAGE

  // epilogue: recombine halves (S2 stored /256), write bf16 loc, fuse col max
#pragma unroll
  for (int n = 0; n < 2; ++n) {
    const int col = bcol + wc * 32 + n * 16 + fr;
    float cm = -3.402823466e38f;
#pragma unroll
    for (int m = 0; m < 2; ++m) {
      const int row = brow + wr * 32 + m * 16 + kg * 4;
#pragma unroll
      for (int r4 = 0; r4 < 4; ++r4) {
        float v = -0.5f * (256.0f * acc[0][m][n][r4] + acc[1][m][n][r4] +
                           qterm[row + r4]);
        loc[(size_t)(row + r4) * BB + col] = f2bf(v);
        cm = fmaxf(cm, v);
      }
    }
    cm = fmaxf(cm, __shfl_xor(cm, 16, 64));
    cm = fmaxf(cm, __shfl_xor(cm, 32, 64));
    if (kg == 0) atomicMax(&Mkey[col], fkey(cm));  // order-invariant
  }
}

// ---------------------------------------------------------------------------
// Kernel 3: wave-per-row LSE + diag (round-15 verbatim).
__global__ __launch_bounds__(256) void row_lse(
    const unsigned short* __restrict__ loc, const unsigned* __restrict__ Mkey,
    float* __restrict__ rowval) {
  const int w = threadIdx.x >> 6, lane = threadIdx.x & 63;
  const int q = blockIdx.x * 4 + w;
  const short8* lp = (const short8*)(loc + (size_t)q * BB);
  const uint4* kp = (const uint4*)Mkey;
  float xs[4][8];
  float m = -3.402823466e38f, dv = 0.f;
#pragma unroll
  for (int c = 0; c < 4; ++c) {
    short8 v = lp[c * 64 + lane];
    uint4 k0 = kp[(c * 64 + lane) * 2];
    uint4 k1 = kp[(c * 64 + lane) * 2 + 1];
    unsigned ks[8] = {k0.x, k0.y, k0.z, k0.w, k1.x, k1.y, k1.z, k1.w};
#pragma unroll
    for (int e = 0; e < 8; ++e) {
      float x = bf2f((unsigned short)v[e]) - funkey(ks[e]);
      xs[c][e] = x;
      m = fmaxf(m, x);
      if (c * 512 + lane * 8 + e == q) dv = x;  // diag (static idx)
    }
  }
  m = wmax(m);
  float s = 0.f;
#pragma unroll
  for (int c = 0; c < 4; ++c)
#pragma unroll
    for (int e = 0; e < 8; ++e) s += fexp(xs[c][e] - m);
  s = wsum(s);
  float d = __shfl(dv, (q >> 3) & 63, 64);
  if (lane == 0) rowval[q] = d - (m + flog(s));
}

// ---------------------------------------------------------------------------
// Kernel 4: loss = -mean_q rowval[q]  (single block)
__global__ __launch_bounds__(256) void final_loss(
    const float* __restrict__ rowval, float* __restrict__ out) {
  __shared__ float sbuf[4];
  const int tid = threadIdx.x;
  float s = 0.f;
#pragma unroll
  for (int i = 0; i < 8; ++i) s += rowval[tid + i * 256];
  s = block_reduce_sum256(s, sbuf);
  if (tid == 0) out[0] = -s * (1.0f / (float)BB);
}

// ---------------------------------------------------------------------------
extern "C" void kernel_launch(void* const* d_in, const int* in_sizes, int n_in,
                              void* d_out, int out_size, void* d_ws, size_t ws_size,
                              hipStream_t stream) {
  const float* qmean = (const float*)d_in[0];
  const float* qls   = (const float*)d_in[1];
  // d_in[2] query_z: cancels (broadcasts on target axis -> drops in colmax+softmax)
  const float* tmean = (const float*)d_in[3];
  const float* tls   = (const float*)d_in[4];
  // d_in[5] target_z: unused by reference
  const float* eps   = (const float*)d_in[6];

  char* ws = (char*)d_ws;
  unsigned char* Acat  = (unsigned char*)(ws + 0);                   // 2 MB
  unsigned char* Bcat  = (unsigned char*)(ws + (2u << 20));          // 2 MB
  float* qterm         = (float*)(ws + (4u << 20));                  // 8 KB
  unsigned* Mkey       = (unsigned*)(ws + (4u << 20) + 8192);        // 8 KB
  float* rowval        = (float*)(ws + (4u << 20) + 16384);          // 8 KB
  unsigned short* loc  = (unsigned short*)(ws + (4u << 20) + 65536); // 8 MB

  prep<<<1024, 256, 0, stream>>>(qmean, qls, tmean, tls, eps,
                                 Acat, Bcat, qterm, Mkey);
  gemm_loc<<<(BB / BM) * (BB / BN), 256, 0, stream>>>(Acat, Bcat, qterm, loc, Mkey);
  row_lse<<<512, 256, 0, stream>>>(loc, Mkey, rowval);
  final_loss<<<1, 256, 0, stream>>>(rowval, (float*)d_out);
}